// Round 14
// baseline (68.837 us; speedup 1.0000x reference)
//
#include <hip/hip_runtime.h>

#define NQ 12
#define NL 4

typedef float f32x2 __attribute__((ext_vector_type(2)));

// ---------------------------------------------------------------------------
// Compile-time CNOT tracking as a GF(2) linear map (rounds 1-13, verified).
// RY(l,q) in tan form: mine'[i] = mine[i] + T(i)*mine[i^mk],
//   T(i) = +t iff parity(rm & i) odd else -t; cos factors -> Ctot^2 at end.
// LAYOUT (r13, verified): ONE element per wave; i = (lane<<6)|(r<<1)|h.
// ROUND 14: kill AGPR spill churn (r13 diag: VGPR_Count=64 for a 64-float
// state => allocator parked state in AGPRs; accvgpr r/w per gate ~= the 2.5x
// instruction bloat). (1) amdgpu_waves_per_eu(4,5): min 4 waves (128-VGPR
// budget), max 5 — removes the 8-wave incentive to shrink VGPRs; (2) all 60
// wave-uniform params -> readfirstlane -> SGPRs (zero VGPR pressure).
// ---------------------------------------------------------------------------
struct MaskTab { int mk[NL][NQ]; int rm[NL][NQ]; int rout[NQ]; };

static constexpr MaskTab build_masks() {
  MaskTab T{};
  unsigned col[NQ] = {};
  unsigned inv[NQ] = {};
  for (int k = 0; k < NQ; ++k) { col[k] = 1u << k; inv[k] = 1u << k; }
  for (int l = 0; l < NL; ++l) {
    for (int q = 0; q < NQ; ++q) {
      const int p = NQ - 1 - q;
      T.mk[l][q] = (int)inv[p];
      int rm = 0;
      for (int k = 0; k < NQ; ++k) rm |= (int)(((col[k] >> p) & 1u) << k);
      T.rm[l][q] = rm;
    }
    for (int q = 0; q < NQ - 1; ++q) {
      const int pc = NQ - 1 - q, pt = NQ - 2 - q;
      for (int k = 0; k < NQ; ++k) col[k] ^= ((col[k] >> pc) & 1u) << pt;
      inv[pc] ^= inv[pt];
    }
  }
  for (int q = 0; q < NQ; ++q) {
    const int p = NQ - 1 - q;
    int rm = 0;
    for (int k = 0; k < NQ; ++k) rm |= (int)(((col[k] >> p) & 1u) << k);
    T.rout[q] = rm;
  }
  return T;
}
static constexpr MaskTab MT = build_masks();

// ---------------- compile-time utils ----------------
constexpr int cpar(int j, int m) { return __builtin_popcount((unsigned)(j & m)) & 1; }
constexpr int chb(int m) { return m ? (1 << (31 - __builtin_clz((unsigned)m))) : 0; }
constexpr bool dpp_ok(int d) { return d==1||d==2||d==3||d==7||d==8||d==15; }
constexpr int dpp_ctrl_for(int d) {
  return d==1?0xB1 : d==2?0x4E : d==3?0x1B : d==7?0x141 : d==8?0x128 : 0x140;
}
// 2-DPP XOR compositions of verified ctrls (r9-verified): 5=7^2,6=7^1,10=8^2,12=15^3
constexpr bool synth2_ok(int d) { return d==5||d==6||d==10||d==12; }
constexpr int synth_a(int d) { return d==5?0x141 : d==6?0x141 : d==10?0x128 : 0x140; }
constexpr int synth_b(int d) { return d==5?0x4E  : d==6?0xB1  : d==10?0x4E  : 0x1B; }

template <int V> struct ic_ { static constexpr int v = V; };
template <int I, int N, typename F>
__device__ __forceinline__ void sfor(F&& f) {
  if constexpr (I < N) { f(ic_<I>{}); sfor<I + 1, N>(f); }
}

// ---------------- cross-lane primitives (verified rounds 4-13) ----------------
template <int CTRL>
__device__ __forceinline__ float dppf(float x) {
  return __int_as_float(__builtin_amdgcn_update_dpp(0, __float_as_int(x), CTRL, 0xF, 0xF, false));
}
template <int PAT>
__device__ __forceinline__ float swzf(float x) {
  return __int_as_float(__builtin_amdgcn_ds_swizzle(__float_as_int(x), PAT));
}
__device__ __forceinline__ float bpermf(int idx_bytes, float x) {
  return __int_as_float(__builtin_amdgcn_ds_bpermute(idx_bytes, __float_as_int(x)));
}
__device__ __forceinline__ float RFL(float x) {
  return __int_as_float(__builtin_amdgcn_readfirstlane(__float_as_int(x)));
}

template <int S0, int S1>
__device__ __forceinline__ f32x2 tsel(float tp, float tn) {
  f32x2 r; r.x = S0 ? tn : tp; r.y = S1 ? tn : tp; return r;
}
__device__ __forceinline__ f32x2 pfma(f32x2 t, f32x2 p, f32x2 s) {
  return __builtin_elementwise_fma(t, p, s);
}

// lane-parity base sign: odd parity -> +t, even -> -t (rounds 2-13 verified).
template <int MASK>
__device__ __forceinline__ float lane_sign(float t, int lane) {
  if constexpr (MASK == 0) return -t;
  else return (__popc(lane & MASK) & 1) ? t : -t;
}

// ---------------- one RY gate (tan form), 1-elem layout ----------------
template <int L, int Q>
__device__ __forceinline__ void gate(f32x2 (&s2)[32], float t, int lane) {
  constexpr int MK  = MT.mk[L][Q];
  constexpr int RM  = MT.rm[L][Q];
  constexpr int MKL = (MK >> 6) & 63;   // lane-xor (6 lane bits)
  constexpr int MKO = MK & 63;          // register+half xor (index bits 0-5)
  constexpr int RMH = (RM >> 6) & 63;
  constexpr int RMO = RM & 63;
  const float tl  = lane_sign<RMH>(t, lane);
  const float tln = -tl;
  constexpr int M2 = MKO >> 1;
  constexpr int HS = MKO & 1;

  if constexpr (MKL == 0 && HS == 0) {
    // packed register butterfly
    constexpr int HB = chb(M2);
    sfor<0, 32>([&](auto RC) {
      constexpr int r0 = decltype(RC)::v;
      if constexpr ((r0 & HB) == 0) {
        constexpr int r1 = r0 ^ M2;
        const f32x2 A = s2[r0], B = s2[r1];
        s2[r0] = pfma(tsel<cpar(2*r0,RMO), cpar(2*r0+1,RMO)>(tl,tln), B, A);
        s2[r1] = pfma(tsel<cpar(2*r1,RMO), cpar(2*r1+1,RMO)>(tl,tln), A, B);
      }
    });
  } else if constexpr (MKL == 0) {
    // half-swap register gates: scalar FMAs
    if constexpr (M2 == 0) {
      sfor<0, 32>([&](auto RC) {
        constexpr int r = decltype(RC)::v;
        const float ax = s2[r].x, ay = s2[r].y;
        s2[r].x = fmaf(cpar(2*r,   RMO) ? tln : tl, ay, ax);
        s2[r].y = fmaf(cpar(2*r+1, RMO) ? tln : tl, ax, ay);
      });
    } else {
      constexpr int HB = chb(M2);
      sfor<0, 32>([&](auto RC) {
        constexpr int r0 = decltype(RC)::v;
        if constexpr ((r0 & HB) == 0) {
          constexpr int r1 = r0 ^ M2;
          const float ax = s2[r0].x, ay = s2[r0].y;
          const float bx = s2[r1].x, by = s2[r1].y;
          s2[r0].x = fmaf(cpar(2*r0,   RMO) ? tln : tl, by, ax);
          s2[r0].y = fmaf(cpar(2*r0+1, RMO) ? tln : tl, bx, ay);
          s2[r1].x = fmaf(cpar(2*r1,   RMO) ? tln : tl, ay, bx);
          s2[r1].y = fmaf(cpar(2*r1+1, RMO) ? tln : tl, ax, by);
        }
      });
    }
  } else {
    // cross-lane gates (MKO even for all such masks): fetch + packed FMA
    const int bidx = (lane ^ MKL) << 2;   // used only by bperm path
    auto F1 = [&](float x) -> float {
      if constexpr (dpp_ok(MKL)) return dppf<dpp_ctrl_for(MKL)>(x);
      else if constexpr (synth2_ok(MKL)) return dppf<synth_b(MKL)>(dppf<synth_a(MKL)>(x));
      else if constexpr (MKL <= 31) return swzf<(MKL << 10) | 0x1F>(x);
      else return bpermf(bidx, x);
    };
    if constexpr (M2 == 0) {
      sfor<0, 32>([&](auto RC) {
        constexpr int r = decltype(RC)::v;
        f32x2 p; p.x = F1(s2[r].x); p.y = F1(s2[r].y);
        s2[r] = pfma(tsel<cpar(2*r,RMO), cpar(2*r+1,RMO)>(tl,tln), p, s2[r]);
      });
    } else {
      constexpr int HB = chb(M2);
      sfor<0, 32>([&](auto RC) {
        constexpr int r0 = decltype(RC)::v;
        if constexpr ((r0 & HB) == 0) {
          constexpr int r1 = r0 ^ M2;
          f32x2 pa; pa.x = F1(s2[r1].x); pa.y = F1(s2[r1].y);
          f32x2 pb; pb.x = F1(s2[r0].x); pb.y = F1(s2[r0].y);
          s2[r0] = pfma(tsel<cpar(2*r0,RMO), cpar(2*r0+1,RMO)>(tl,tln), pa, s2[r0]);
          s2[r1] = pfma(tsel<cpar(2*r1,RMO), cpar(2*r1+1,RMO)>(tl,tln), pb, s2[r1]);
        }
      });
    }
  }
}

template <int L, int Q>
__device__ __forceinline__ void round_rec(f32x2 (&s2)[32], const float (&t)[NQ], int lane) {
  if constexpr (Q < NQ) {
    gate<L, Q>(s2, t[Q], lane);
    round_rec<L, Q + 1>(s2, t, lane);
  }
}

__global__ __launch_bounds__(256)
__attribute__((amdgpu_waves_per_eu(4, 5)))
void vqc_kernel(const float* __restrict__ ang,
                const float* __restrict__ thetas,
                float* __restrict__ out, int B) {
  const int tid  = blockIdx.x * blockDim.x + threadIdx.x;
  const int w    = tid >> 6;          // batch element = wave
  const int lane = tid & 63;
  const int row  = (w < B) ? w : (B - 1);   // clamp, no early exit (barrier safety)

  // ---- distributed angle prep -> per-wave LDS slab (r10/r13-verified) ----
  // [0..35] tan(l=1..3,q) ; [36..47] c0 ; [48..59] s0
  __shared__ float prep[4][64];
  float* P = &prep[threadIdx.x >> 6][0];

  float csprod = 1.0f;
  if (lane < 36) {
    const int l = 1 + lane / 12, q = lane % 12;
    float sn, cs;
    __sincosf(0.5f * (ang[row * NQ + q] + thetas[l * NQ + q]), &sn, &cs);
    P[lane] = __fdividef(sn, cs);
    csprod = cs;
  } else if (lane < 48) {
    const int q = lane - 36;
    float sn, cs;
    __sincosf(0.5f * (ang[row * NQ + q] + thetas[q]), &sn, &cs);
    P[36 + q] = cs;
    P[48 + q] = sn;
  }
  // full-wave product reduce (verified xor patterns)
  csprod *= dppf<0xB1>(csprod);
  csprod *= dppf<0x4E>(csprod);
  csprod *= swzf<(4 << 10) | 0x1F>(csprod);
  csprod *= dppf<0x128>(csprod);
  csprod *= swzf<(16 << 10) | 0x1F>(csprod);
  csprod *= bpermf((lane ^ 32) << 2, csprod);
  const float Csq = csprod * csprod;
  __syncthreads();

  // ---- params are wave-uniform: LDS -> readfirstlane -> SGPRs ----
  const float4* P4 = (const float4*)P;
  float tA[NQ], tB[NQ], tC[NQ], c0[NQ], s0[NQ];
#define LD4S(arr, base, idx) { float4 v_ = P4[idx]; \
  arr[base+0] = RFL(v_.x); arr[base+1] = RFL(v_.y); \
  arr[base+2] = RFL(v_.z); arr[base+3] = RFL(v_.w); }
  LD4S(tA, 0, 0) LD4S(tA, 4, 1) LD4S(tA, 8, 2)
  LD4S(tB, 0, 3) LD4S(tB, 4, 4) LD4S(tB, 8, 5)
  LD4S(tC, 0, 6) LD4S(tC, 4, 7) LD4S(tC, 8, 8)
  LD4S(c0, 0, 9)  LD4S(c0, 4, 10) LD4S(c0, 8, 11)
  LD4S(s0, 0, 12) LD4S(s0, 4, 13) LD4S(s0, 8, 14)
#undef LD4S

  // ---- layer 0 on |0..0>: product state (r8/r13-verified index map) ----
  // lane bit k -> qubit 5-k ; reg bit k -> qubit 10-k ; half bit -> qubit 11
  f32x2 s2[32];
  {
    float flane = 1.0f;
    #pragma unroll
    for (int k = 0; k < 6; ++k) {
      flane *= ((lane >> k) & 1) ? s0[5 - k] : c0[5 - k];
    }
    { f32x2 h0; h0.x = c0[11] * flane; h0.y = s0[11] * flane; s2[0] = h0; }
    #pragma unroll
    for (int k = 0; k < 5; ++k) {
      const int W = 1 << k;
      #pragma unroll
      for (int j = 0; j < 32; ++j) {
        if (j >= W) continue;
        s2[j + W] = s2[j] * s0[10 - k];
        s2[j]     = s2[j] * c0[10 - k];
      }
    }
  }

  // ---- layers 1-3 (tan form), params from SGPRs ----
  round_rec<1, 0>(s2, tA, lane);
  round_rec<2, 0>(s2, tB, lane);
  round_rec<3, 0>(s2, tC, lane);

  // probabilities (unscaled)
  #pragma unroll
  for (int r = 0; r < 32; ++r) s2[r] = s2[r] * s2[r];

  // Walsh-Hadamard over the 6 register-dim bits
  #pragma unroll
  for (int r = 0; r < 32; ++r) {
    const float u = s2[r].x, v = s2[r].y;
    s2[r].x = u + v;
    s2[r].y = u - v;
  }
  #pragma unroll
  for (int b = 0; b < 5; ++b) {
    const int W = 1 << b;
    #pragma unroll
    for (int r0 = 0; r0 < 32; ++r0) {
      if (r0 & W) continue;
      const int r1 = r0 | W;
      const f32x2 u = s2[r0], v = s2[r1];
      s2[r0] = u + v;
      s2[r1] = u - v;
    }
  }

  // ---- epilogue: 12 signed full-wave reductions ----
  sfor<0, NQ>([&](auto QC) {
    constexpr int q   = decltype(QC)::v;
    constexpr int RM  = MT.rout[q];
    constexpr int RMH = (RM >> 6) & 63;
    constexpr int RMO = RM & 63;
    float v = (RMO & 1) ? s2[RMO >> 1].y : s2[RMO >> 1].x;
    if constexpr (RMH != 0) {
      const int sx = (__popc(lane & RMH) & 1) << 31;
      v = __int_as_float(__float_as_int(v) ^ sx);
    }
    v += dppf<0xB1>(v);               // xor1
    v += dppf<0x4E>(v);               // xor2
    v += swzf<(4 << 10) | 0x1F>(v);   // xor4
    v += dppf<0x128>(v);              // xor8
    v += swzf<(16 << 10) | 0x1F>(v);  // xor16
    v += bpermf((lane ^ 32) << 2, v); // xor32
    if (lane == 0 && w < B) out[w * NQ + q] = v * Csq;
  });
}

extern "C" void kernel_launch(void* const* d_in, const int* in_sizes, int n_in,
                              void* d_out, int out_size, void* d_ws, size_t ws_size,
                              hipStream_t stream) {
  const float* ang    = (const float*)d_in[0];
  const float* thetas = (const float*)d_in[1];
  float* out          = (float*)d_out;
  const int B = in_sizes[0] / NQ;
  const int threads = 256;                       // 4 waves/block, 1 element/wave
  const int blocks = (B * 64 + threads - 1) / threads;
  hipLaunchKernelGGL(vqc_kernel, dim3(blocks), dim3(threads), 0, stream,
                     ang, thetas, out, B);
}

// Round 15
// 67.979 us; speedup vs baseline: 1.0126x; 1.0126x over previous
//
#include <hip/hip_runtime.h>

#define NQ 12
#define NL 4

typedef float f32x2 __attribute__((ext_vector_type(2)));

// ---------------------------------------------------------------------------
// Compile-time CNOT tracking as a GF(2) linear map (rounds 1-14, verified).
// RY(l,q) in tan form: mine'[i] = mine[i] + T(i)*mine[i^mk],
//   T(i) = +t iff parity(rm & i) odd else -t; cos factors -> Ctot^2 at end.
// LAYOUT (r9-r11, verified): TWO batch elements per wave.
//   physical lane = (elem << 5) | l5;  global index i = (l5 << 7) | (r<<1) | h
// ROUND 15: r11 source verbatim, ONE change — amdgpu_waves_per_eu(3,3).
// r11 ran at exactly 128 VGPR (state fills the whole file, zero scheduling
// headroom, fetch->FMA chains serialized). Target 3 waves/SIMD -> 170-VGPR
// budget -> state + temps fit with slack. Single-variable A/B for the
// register-starvation hypothesis (r12 confounded this with 2 other changes).
// ---------------------------------------------------------------------------
struct MaskTab { int mk[NL][NQ]; int rm[NL][NQ]; int rout[NQ]; };

static constexpr MaskTab build_masks() {
  MaskTab T{};
  unsigned col[NQ] = {};
  unsigned inv[NQ] = {};
  for (int k = 0; k < NQ; ++k) { col[k] = 1u << k; inv[k] = 1u << k; }
  for (int l = 0; l < NL; ++l) {
    for (int q = 0; q < NQ; ++q) {
      const int p = NQ - 1 - q;
      T.mk[l][q] = (int)inv[p];
      int rm = 0;
      for (int k = 0; k < NQ; ++k) rm |= (int)(((col[k] >> p) & 1u) << k);
      T.rm[l][q] = rm;
    }
    for (int q = 0; q < NQ - 1; ++q) {
      const int pc = NQ - 1 - q, pt = NQ - 2 - q;
      for (int k = 0; k < NQ; ++k) col[k] ^= ((col[k] >> pc) & 1u) << pt;
      inv[pc] ^= inv[pt];
    }
  }
  for (int q = 0; q < NQ; ++q) {
    const int p = NQ - 1 - q;
    int rm = 0;
    for (int k = 0; k < NQ; ++k) rm |= (int)(((col[k] >> p) & 1u) << k);
    T.rout[q] = rm;
  }
  return T;
}
static constexpr MaskTab MT = build_masks();

// ---------------- compile-time utils ----------------
constexpr int cpar(int j, int m) { return __builtin_popcount((unsigned)(j & m)) & 1; }
constexpr int chb(int m) { return m ? (1 << (31 - __builtin_clz((unsigned)m))) : 0; }
constexpr bool dpp_ok(int d) { return d==1||d==2||d==3||d==7||d==8||d==15; }
constexpr int dpp_ctrl_for(int d) {
  return d==1?0xB1 : d==2?0x4E : d==3?0x1B : d==7?0x141 : d==8?0x128 : 0x140;
}
// 2-DPP compositions kept on VALU: 6=7^1, 12=15^3 (as in r11; 5,10 stay on DS)
constexpr bool synth2_ok(int d) { return d==6||d==12; }
constexpr int synth_a(int d) { return d==6?0x141 : 0x140; }
constexpr int synth_b(int d) { return d==6?0xB1  : 0x1B; }

template <int V> struct ic_ { static constexpr int v = V; };
template <int I, int N, typename F>
__device__ __forceinline__ void sfor(F&& f) {
  if constexpr (I < N) { f(ic_<I>{}); sfor<I + 1, N>(f); }
}

// ---------------- cross-lane primitives (verified rounds 4-14) -------
template <int CTRL>
__device__ __forceinline__ float dppf(float x) {
  return __int_as_float(__builtin_amdgcn_update_dpp(0, __float_as_int(x), CTRL, 0xF, 0xF, false));
}
template <int PAT>
__device__ __forceinline__ float swzf(float x) {
  return __int_as_float(__builtin_amdgcn_ds_swizzle(__float_as_int(x), PAT));
}

__device__ __forceinline__ f32x2 pfma(f32x2 t, f32x2 p, f32x2 s) {
  return __builtin_elementwise_fma(t, p, s);
}

// lane-parity base sign: odd parity -> +t, even -> -t (rounds 2-14 verified).
template <int MASK>
__device__ __forceinline__ float lane_sign(float t, int lane) {
  if constexpr (MASK == 0) return -t;
  else return (__popc(lane & MASK) & 1) ? t : -t;
}

// ---------------- one RY gate (tan form), 2-elem layout ----------------
template <int L, int Q>
__device__ __forceinline__ void gate(f32x2 (&s2)[64], float t, int lane) {
  constexpr int MK  = MT.mk[L][Q];
  constexpr int RM  = MT.rm[L][Q];
  constexpr int MKL = (MK >> 7) & 31;   // lane-xor (physical lane bits 0-4)
  constexpr int MKO = MK & 127;         // register+half xor (index bits 0-6)
  constexpr int RMH = (RM >> 7) & 31;
  constexpr int RMO = RM & 127;
  const float tl  = lane_sign<RMH>(t, lane);
  const float tln = -tl;
  constexpr int M2 = MKO >> 1;   // f32x2-register xor
  constexpr int HS = MKO & 1;    // half swap (index bit 0)

  if constexpr (MKL == 0 && HS == 0) {
    // ---- packed register butterfly; RMO even -> per-register uniform sign ----
    f32x2 tp; tp.x = tl;  tp.y = tl;
    f32x2 tn; tn.x = tln; tn.y = tln;
    constexpr int HB = chb(M2);
    sfor<0, 64>([&](auto RC) {
      constexpr int r0 = decltype(RC)::v;
      if constexpr ((r0 & HB) == 0) {
        constexpr int r1 = r0 ^ M2;
        const f32x2 A = s2[r0], B = s2[r1];
        s2[r0] = pfma(cpar(2*r0, RMO) ? tn : tp, B, A);
        s2[r1] = pfma(cpar(2*r1, RMO) ? tn : tp, A, B);
      }
    });
  } else if constexpr (MKL == 0) {
    // ---- half-swap register gates: scalar FMAs ----
    if constexpr (M2 == 0) {
      sfor<0, 64>([&](auto RC) {
        constexpr int r = decltype(RC)::v;
        const float ax = s2[r].x, ay = s2[r].y;
        s2[r].x = fmaf(cpar(2*r,   RMO) ? tln : tl, ay, ax);
        s2[r].y = fmaf(cpar(2*r+1, RMO) ? tln : tl, ax, ay);
      });
    } else {
      constexpr int HB = chb(M2);
      sfor<0, 64>([&](auto RC) {
        constexpr int r0 = decltype(RC)::v;
        if constexpr ((r0 & HB) == 0) {
          constexpr int r1 = r0 ^ M2;
          const float ax = s2[r0].x, ay = s2[r0].y;
          const float bx = s2[r1].x, by = s2[r1].y;
          s2[r0].x = fmaf(cpar(2*r0,   RMO) ? tln : tl, by, ax);
          s2[r0].y = fmaf(cpar(2*r0+1, RMO) ? tln : tl, bx, ay);
          s2[r1].x = fmaf(cpar(2*r1,   RMO) ? tln : tl, ay, bx);
          s2[r1].y = fmaf(cpar(2*r1+1, RMO) ? tln : tl, ax, by);
        }
      });
    }
  } else if constexpr (dpp_ok(MKL) || synth2_ok(MKL)) {
    // ---- DPP-path cross gates: scalar tied-dst form ----
    auto D = [&](float x) -> float {
      if constexpr (dpp_ok(MKL)) return dppf<dpp_ctrl_for(MKL)>(x);
      else return dppf<synth_b(MKL)>(dppf<synth_a(MKL)>(x));
    };
    if constexpr (M2 == 0) {
      sfor<0, 64>([&](auto RC) {
        constexpr int r = decltype(RC)::v;
        const float sr = cpar(2*r, RMO) ? tln : tl;
        s2[r].x = fmaf(D(s2[r].x), sr, s2[r].x);
        s2[r].y = fmaf(D(s2[r].y), sr, s2[r].y);
      });
    } else {
      constexpr int HB = chb(M2);
      sfor<0, 64>([&](auto RC) {
        constexpr int r0 = decltype(RC)::v;
        if constexpr ((r0 & HB) == 0) {
          constexpr int r1 = r0 ^ M2;
          const float s0v = cpar(2*r0, RMO) ? tln : tl;
          const float s1v = cpar(2*r1, RMO) ? tln : tl;
          const float ax = s2[r0].x, ay = s2[r0].y;
          const float bx = s2[r1].x, by = s2[r1].y;
          s2[r0].x = fmaf(D(bx), s0v, ax);
          s2[r0].y = fmaf(D(by), s0v, ay);
          s2[r1].x = fmaf(D(ax), s1v, bx);
          s2[r1].y = fmaf(D(ay), s1v, by);
        }
      });
    }
  } else {
    // ---- DS swizzle cross gates (masks 5,10,20,24,30; MKO even) ----
    constexpr int PAT = (MKL << 10) | 0x1F;
    f32x2 tp; tp.x = tl;  tp.y = tl;
    f32x2 tn; tn.x = tln; tn.y = tln;
    if constexpr (M2 == 0) {
      sfor<0, 64>([&](auto RC) {
        constexpr int r = decltype(RC)::v;
        f32x2 p; p.x = swzf<PAT>(s2[r].x); p.y = swzf<PAT>(s2[r].y);
        s2[r] = pfma(cpar(2*r, RMO) ? tn : tp, p, s2[r]);
      });
    } else {
      constexpr int HB = chb(M2);
      sfor<0, 64>([&](auto RC) {
        constexpr int r0 = decltype(RC)::v;
        if constexpr ((r0 & HB) == 0) {
          constexpr int r1 = r0 ^ M2;
          f32x2 pa; pa.x = swzf<PAT>(s2[r1].x); pa.y = swzf<PAT>(s2[r1].y);
          f32x2 pb; pb.x = swzf<PAT>(s2[r0].x); pb.y = swzf<PAT>(s2[r0].y);
          s2[r0] = pfma(cpar(2*r0, RMO) ? tn : tp, pa, s2[r0]);
          s2[r1] = pfma(cpar(2*r1, RMO) ? tn : tp, pb, s2[r1]);
        }
      });
    }
  }
}

template <int L, int Q>
__device__ __forceinline__ void round_rec(f32x2 (&s2)[64], const float (&t)[NQ], int lane) {
  if constexpr (Q < NQ) {
    gate<L, Q>(s2, t[Q], lane);
    round_rec<L, Q + 1>(s2, t, lane);
  }
}

__global__ __launch_bounds__(256)
__attribute__((amdgpu_waves_per_eu(3, 3)))
void vqc_kernel(const float* __restrict__ ang,
                const float* __restrict__ thetas,
                float* __restrict__ out, int B) {
  const int tid  = blockIdx.x * blockDim.x + threadIdx.x;
  const int gw   = tid >> 6;          // wave index: elements 2gw, 2gw+1
  const int lane = tid & 63;
  const int l5   = lane & 31;
  const int elem = lane >> 5;
  const int row_store = 2 * gw + elem;
  const int row = (row_store < B) ? row_store : (B - 1);   // clamp, no early exit

  // ---- distributed angle prep -> per-wave LDS slab (r10/r11 verified) ----
  // slab per element (64 floats): [0..35] tan(l=1..3,q), [36..47] c0, [48..59] s0
  __shared__ float prep[4][2][64];
  const int wib = threadIdx.x >> 6;
  float* P = &prep[wib][elem][0];

  float csprod;
  {
    const int tau1 = l5;
    const int lq1 = (1 + tau1 / 12) * NQ + (tau1 % 12);
    float sn, cs;
    __sincosf(0.5f * (ang[row * NQ + (tau1 % 12)] + thetas[lq1]), &sn, &cs);
    P[tau1] = __fdividef(sn, cs);
    csprod = cs;
    if (l5 < 16) {
      const int tau2 = l5 + 32;
      if (tau2 < 36) {
        const int q2 = tau2 % 12;
        float sn2, cs2;
        __sincosf(0.5f * (ang[row * NQ + q2] + thetas[3 * NQ + q2]), &sn2, &cs2);
        P[tau2] = __fdividef(sn2, cs2);
        csprod *= cs2;
      } else {
        const int q2 = tau2 - 36;
        float sn2, cs2;
        __sincosf(0.5f * (ang[row * NQ + q2] + thetas[q2]), &sn2, &cs2);
        P[36 + q2] = cs2;
        P[48 + q2] = sn2;
      }
    }
    csprod *= dppf<0xB1>(csprod);
    csprod *= dppf<0x4E>(csprod);
    csprod *= swzf<(4 << 10) | 0x1F>(csprod);
    csprod *= dppf<0x128>(csprod);
    csprod *= swzf<(16 << 10) | 0x1F>(csprod);
  }
  const float Csq = csprod * csprod;
  __syncthreads();

  // vector read-back (broadcast reads, conflict-free)
  float t1[NQ], t2[NQ], t3[NQ], c0[NQ], s0[NQ];
  {
    const float4* P4 = (const float4*)P;
#define LD4(arr, base, idx) { float4 v = P4[idx]; arr[base]=v.x; arr[base+1]=v.y; arr[base+2]=v.z; arr[base+3]=v.w; }
    LD4(t1, 0, 0) LD4(t1, 4, 1) LD4(t1, 8, 2)
    LD4(t2, 0, 3) LD4(t2, 4, 4) LD4(t2, 8, 5)
    LD4(t3, 0, 6) LD4(t3, 4, 7) LD4(t3, 8, 8)
    LD4(c0, 0, 9) LD4(c0, 4, 10) LD4(c0, 8, 11)
    LD4(s0, 0, 12) LD4(s0, 4, 13) LD4(s0, 8, 14)
#undef LD4
  }

  // ---- layer 0 on |0..0>: per-element product state (rounds 9-11 verified) ----
  float flane = 1.0f;
  #pragma unroll
  for (int k = 0; k < 5; ++k) {
    flane *= ((l5 >> k) & 1) ? s0[4 - k] : c0[4 - k];
  }
  f32x2 s2[64];
  { f32x2 h0; h0.x = c0[11] * flane; h0.y = s0[11] * flane; s2[0] = h0; }
  #pragma unroll
  for (int k = 0; k < 6; ++k) {
    const int W = 1 << k;
    #pragma unroll
    for (int j = 0; j < 64; ++j) {
      if (j >= W) continue;
      s2[j + W] = s2[j] * s0[10 - k];
      s2[j]     = s2[j] * c0[10 - k];
    }
  }

  // ---- layers 1-3 (tan form) ----
  round_rec<1, 0>(s2, t1, lane);
  round_rec<2, 0>(s2, t2, lane);
  round_rec<3, 0>(s2, t3, lane);

  // probabilities (unscaled, packed)
  #pragma unroll
  for (int r = 0; r < 64; ++r) s2[r] = s2[r] * s2[r];

  // Walsh-Hadamard over the 7 register-dim bits
  #pragma unroll
  for (int r = 0; r < 64; ++r) {
    const float u = s2[r].x, v = s2[r].y;
    s2[r].x = u + v;
    s2[r].y = u - v;
  }
  #pragma unroll
  for (int b = 0; b < 6; ++b) {
    const int W = 1 << b;
    #pragma unroll
    for (int r0 = 0; r0 < 64; ++r0) {
      if (r0 & W) continue;
      const int r1 = r0 | W;
      const f32x2 u = s2[r0], v = s2[r1];
      s2[r0] = u + v;
      s2[r1] = u - v;
    }
  }

  // ---- epilogue: 12 signed reductions over lane bits 0-4 (per element) ----
  sfor<0, NQ>([&](auto QC) {
    constexpr int q   = decltype(QC)::v;
    constexpr int RM  = MT.rout[q];
    constexpr int RMH = (RM >> 7) & 31;
    constexpr int RMO = RM & 127;
    float v = (RMO & 1) ? s2[RMO >> 1].y : s2[RMO >> 1].x;
    if constexpr (RMH != 0) {
      const int sx = (__popc(lane & RMH) & 1) << 31;  // odd lane parity -> minus
      v = __int_as_float(__float_as_int(v) ^ sx);
    }
    v += dppf<0xB1>(v);               // xor1
    v += dppf<0x4E>(v);               // xor2
    v += swzf<(4 << 10) | 0x1F>(v);   // xor4
    v += dppf<0x128>(v);              // xor8
    v += swzf<(16 << 10) | 0x1F>(v);  // xor16 (within 32-lane group)
    if (l5 == 0 && row_store < B) out[row_store * NQ + q] = v * Csq;
  });
}

extern "C" void kernel_launch(void* const* d_in, const int* in_sizes, int n_in,
                              void* d_out, int out_size, void* d_ws, size_t ws_size,
                              hipStream_t stream) {
  const float* ang    = (const float*)d_in[0];
  const float* thetas = (const float*)d_in[1];
  float* out          = (float*)d_out;
  const int B = in_sizes[0] / NQ;
  const int waves = (B + 1) / 2;       // 2 elements per wave
  const int threads = 256;
  const int blocks = (waves * 64 + threads - 1) / threads;
  hipLaunchKernelGGL(vqc_kernel, dim3(blocks), dim3(threads), 0, stream,
                     ang, thetas, out, B);
}

// Round 16
// 59.785 us; speedup vs baseline: 1.1514x; 1.1371x over previous
//
#include <hip/hip_runtime.h>

#define NQ 12
#define NL 4

typedef float f32x2 __attribute__((ext_vector_type(2)));

// ---------------------------------------------------------------------------
// Compile-time CNOT tracking as a GF(2) linear map (rounds 1-15, verified).
// RY(l,q) in tan form: mine'[i] = mine[i] + T(i)*mine[i^mk],
//   T(i) = +t iff parity(rm & i) odd else -t; cos factors -> Ctot^2 at end.
// LAYOUT (r9-r11, verified): TWO batch elements per wave.
//   physical lane = (elem << 5) | l5;  global index i = (l5 << 7) | (r<<1) | h
// ROUND 16: r11 source verbatim, ONE change — pfma emits v_pk_fma_f32 via
// plain inline asm (no modifiers / no op_sel; those r6 paths stay dead).
// Tests whether __builtin_elementwise_fma was scalarizing (cycle model says
// r11's ~12k instrs/wave matches scalarized f32x2 math exactly).
// ---------------------------------------------------------------------------
struct MaskTab { int mk[NL][NQ]; int rm[NL][NQ]; int rout[NQ]; };

static constexpr MaskTab build_masks() {
  MaskTab T{};
  unsigned col[NQ] = {};
  unsigned inv[NQ] = {};
  for (int k = 0; k < NQ; ++k) { col[k] = 1u << k; inv[k] = 1u << k; }
  for (int l = 0; l < NL; ++l) {
    for (int q = 0; q < NQ; ++q) {
      const int p = NQ - 1 - q;
      T.mk[l][q] = (int)inv[p];
      int rm = 0;
      for (int k = 0; k < NQ; ++k) rm |= (int)(((col[k] >> p) & 1u) << k);
      T.rm[l][q] = rm;
    }
    for (int q = 0; q < NQ - 1; ++q) {
      const int pc = NQ - 1 - q, pt = NQ - 2 - q;
      for (int k = 0; k < NQ; ++k) col[k] ^= ((col[k] >> pc) & 1u) << pt;
      inv[pc] ^= inv[pt];
    }
  }
  for (int q = 0; q < NQ; ++q) {
    const int p = NQ - 1 - q;
    int rm = 0;
    for (int k = 0; k < NQ; ++k) rm |= (int)(((col[k] >> p) & 1u) << k);
    T.rout[q] = rm;
  }
  return T;
}
static constexpr MaskTab MT = build_masks();

// ---------------- compile-time utils ----------------
constexpr int cpar(int j, int m) { return __builtin_popcount((unsigned)(j & m)) & 1; }
constexpr int chb(int m) { return m ? (1 << (31 - __builtin_clz((unsigned)m))) : 0; }
constexpr bool dpp_ok(int d) { return d==1||d==2||d==3||d==7||d==8||d==15; }
constexpr int dpp_ctrl_for(int d) {
  return d==1?0xB1 : d==2?0x4E : d==3?0x1B : d==7?0x141 : d==8?0x128 : 0x140;
}
// 2-DPP compositions kept on VALU: 6=7^1, 12=15^3 (5,10 stay on DS, as r11)
constexpr bool synth2_ok(int d) { return d==6||d==12; }
constexpr int synth_a(int d) { return d==6?0x141 : 0x140; }
constexpr int synth_b(int d) { return d==6?0xB1  : 0x1B; }

template <int V> struct ic_ { static constexpr int v = V; };
template <int I, int N, typename F>
__device__ __forceinline__ void sfor(F&& f) {
  if constexpr (I < N) { f(ic_<I>{}); sfor<I + 1, N>(f); }
}

// ---------------- cross-lane primitives (verified rounds 4-15) -------
template <int CTRL>
__device__ __forceinline__ float dppf(float x) {
  return __int_as_float(__builtin_amdgcn_update_dpp(0, __float_as_int(x), CTRL, 0xF, 0xF, false));
}
template <int PAT>
__device__ __forceinline__ float swzf(float x) {
  return __int_as_float(__builtin_amdgcn_ds_swizzle(__float_as_int(x), PAT));
}

// ROUND 16: plain packed FMA via inline asm — d = t*p + s, no modifiers.
// Pure VALU op with declared operands; compiler owns dependency tracking.
__device__ __forceinline__ f32x2 pfma(f32x2 t, f32x2 p, f32x2 s) {
  f32x2 d;
  asm("v_pk_fma_f32 %0, %1, %2, %3" : "=v"(d) : "v"(t), "v"(p), "v"(s));
  return d;
}

// lane-parity base sign: odd parity -> +t, even -> -t (rounds 2-15 verified).
template <int MASK>
__device__ __forceinline__ float lane_sign(float t, int lane) {
  if constexpr (MASK == 0) return -t;
  else return (__popc(lane & MASK) & 1) ? t : -t;
}

// ---------------- one RY gate (tan form), 2-elem layout ----------------
template <int L, int Q>
__device__ __forceinline__ void gate(f32x2 (&s2)[64], float t, int lane) {
  constexpr int MK  = MT.mk[L][Q];
  constexpr int RM  = MT.rm[L][Q];
  constexpr int MKL = (MK >> 7) & 31;   // lane-xor (physical lane bits 0-4)
  constexpr int MKO = MK & 127;         // register+half xor (index bits 0-6)
  constexpr int RMH = (RM >> 7) & 31;
  constexpr int RMO = RM & 127;
  const float tl  = lane_sign<RMH>(t, lane);
  const float tln = -tl;
  constexpr int M2 = MKO >> 1;   // f32x2-register xor
  constexpr int HS = MKO & 1;    // half swap (index bit 0)

  if constexpr (MKL == 0 && HS == 0) {
    // ---- packed register butterfly; RMO even -> per-register uniform sign ----
    f32x2 tp; tp.x = tl;  tp.y = tl;
    f32x2 tn; tn.x = tln; tn.y = tln;
    constexpr int HB = chb(M2);
    sfor<0, 64>([&](auto RC) {
      constexpr int r0 = decltype(RC)::v;
      if constexpr ((r0 & HB) == 0) {
        constexpr int r1 = r0 ^ M2;
        const f32x2 A = s2[r0], B = s2[r1];
        s2[r0] = pfma(cpar(2*r0, RMO) ? tn : tp, B, A);
        s2[r1] = pfma(cpar(2*r1, RMO) ? tn : tp, A, B);
      }
    });
  } else if constexpr (MKL == 0) {
    // ---- half-swap register gates: scalar FMAs ----
    if constexpr (M2 == 0) {
      sfor<0, 64>([&](auto RC) {
        constexpr int r = decltype(RC)::v;
        const float ax = s2[r].x, ay = s2[r].y;
        s2[r].x = fmaf(cpar(2*r,   RMO) ? tln : tl, ay, ax);
        s2[r].y = fmaf(cpar(2*r+1, RMO) ? tln : tl, ax, ay);
      });
    } else {
      constexpr int HB = chb(M2);
      sfor<0, 64>([&](auto RC) {
        constexpr int r0 = decltype(RC)::v;
        if constexpr ((r0 & HB) == 0) {
          constexpr int r1 = r0 ^ M2;
          const float ax = s2[r0].x, ay = s2[r0].y;
          const float bx = s2[r1].x, by = s2[r1].y;
          s2[r0].x = fmaf(cpar(2*r0,   RMO) ? tln : tl, by, ax);
          s2[r0].y = fmaf(cpar(2*r0+1, RMO) ? tln : tl, bx, ay);
          s2[r1].x = fmaf(cpar(2*r1,   RMO) ? tln : tl, ay, bx);
          s2[r1].y = fmaf(cpar(2*r1+1, RMO) ? tln : tl, ax, by);
        }
      });
    }
  } else if constexpr (dpp_ok(MKL) || synth2_ok(MKL)) {
    // ---- DPP-path cross gates: scalar tied-dst form ----
    auto D = [&](float x) -> float {
      if constexpr (dpp_ok(MKL)) return dppf<dpp_ctrl_for(MKL)>(x);
      else return dppf<synth_b(MKL)>(dppf<synth_a(MKL)>(x));
    };
    if constexpr (M2 == 0) {
      sfor<0, 64>([&](auto RC) {
        constexpr int r = decltype(RC)::v;
        const float sr = cpar(2*r, RMO) ? tln : tl;
        s2[r].x = fmaf(D(s2[r].x), sr, s2[r].x);
        s2[r].y = fmaf(D(s2[r].y), sr, s2[r].y);
      });
    } else {
      constexpr int HB = chb(M2);
      sfor<0, 64>([&](auto RC) {
        constexpr int r0 = decltype(RC)::v;
        if constexpr ((r0 & HB) == 0) {
          constexpr int r1 = r0 ^ M2;
          const float s0v = cpar(2*r0, RMO) ? tln : tl;
          const float s1v = cpar(2*r1, RMO) ? tln : tl;
          const float ax = s2[r0].x, ay = s2[r0].y;
          const float bx = s2[r1].x, by = s2[r1].y;
          s2[r0].x = fmaf(D(bx), s0v, ax);
          s2[r0].y = fmaf(D(by), s0v, ay);
          s2[r1].x = fmaf(D(ax), s1v, bx);
          s2[r1].y = fmaf(D(ay), s1v, by);
        }
      });
    }
  } else {
    // ---- DS swizzle cross gates (masks 5,10,20,24,30; MKO even) ----
    constexpr int PAT = (MKL << 10) | 0x1F;
    f32x2 tp; tp.x = tl;  tp.y = tl;
    f32x2 tn; tn.x = tln; tn.y = tln;
    if constexpr (M2 == 0) {
      sfor<0, 64>([&](auto RC) {
        constexpr int r = decltype(RC)::v;
        f32x2 p; p.x = swzf<PAT>(s2[r].x); p.y = swzf<PAT>(s2[r].y);
        s2[r] = pfma(cpar(2*r, RMO) ? tn : tp, p, s2[r]);
      });
    } else {
      constexpr int HB = chb(M2);
      sfor<0, 64>([&](auto RC) {
        constexpr int r0 = decltype(RC)::v;
        if constexpr ((r0 & HB) == 0) {
          constexpr int r1 = r0 ^ M2;
          f32x2 pa; pa.x = swzf<PAT>(s2[r1].x); pa.y = swzf<PAT>(s2[r1].y);
          f32x2 pb; pb.x = swzf<PAT>(s2[r0].x); pb.y = swzf<PAT>(s2[r0].y);
          s2[r0] = pfma(cpar(2*r0, RMO) ? tn : tp, pa, s2[r0]);
          s2[r1] = pfma(cpar(2*r1, RMO) ? tn : tp, pb, s2[r1]);
        }
      });
    }
  }
}

template <int L, int Q>
__device__ __forceinline__ void round_rec(f32x2 (&s2)[64], const float (&t)[NQ], int lane) {
  if constexpr (Q < NQ) {
    gate<L, Q>(s2, t[Q], lane);
    round_rec<L, Q + 1>(s2, t, lane);
  }
}

__global__ __launch_bounds__(256, 2) void vqc_kernel(const float* __restrict__ ang,
                                                     const float* __restrict__ thetas,
                                                     float* __restrict__ out, int B) {
  const int tid  = blockIdx.x * blockDim.x + threadIdx.x;
  const int gw   = tid >> 6;          // wave index: elements 2gw, 2gw+1
  const int lane = tid & 63;
  const int l5   = lane & 31;
  const int elem = lane >> 5;
  const int row_store = 2 * gw + elem;
  const int row = (row_store < B) ? row_store : (B - 1);   // clamp, no early exit

  // ---- distributed angle prep -> per-wave LDS slab (r10/r11 verified) ----
  // slab per element (64 floats): [0..35] tan(l=1..3,q), [36..47] c0, [48..59] s0
  __shared__ float prep[4][2][64];
  const int wib = threadIdx.x >> 6;
  float* P = &prep[wib][elem][0];

  float csprod;
  {
    const int tau1 = l5;
    const int lq1 = (1 + tau1 / 12) * NQ + (tau1 % 12);
    float sn, cs;
    __sincosf(0.5f * (ang[row * NQ + (tau1 % 12)] + thetas[lq1]), &sn, &cs);
    P[tau1] = __fdividef(sn, cs);
    csprod = cs;
    if (l5 < 16) {
      const int tau2 = l5 + 32;
      if (tau2 < 36) {
        const int q2 = tau2 % 12;
        float sn2, cs2;
        __sincosf(0.5f * (ang[row * NQ + q2] + thetas[3 * NQ + q2]), &sn2, &cs2);
        P[tau2] = __fdividef(sn2, cs2);
        csprod *= cs2;
      } else {
        const int q2 = tau2 - 36;
        float sn2, cs2;
        __sincosf(0.5f * (ang[row * NQ + q2] + thetas[q2]), &sn2, &cs2);
        P[36 + q2] = cs2;
        P[48 + q2] = sn2;
      }
    }
    csprod *= dppf<0xB1>(csprod);
    csprod *= dppf<0x4E>(csprod);
    csprod *= swzf<(4 << 10) | 0x1F>(csprod);
    csprod *= dppf<0x128>(csprod);
    csprod *= swzf<(16 << 10) | 0x1F>(csprod);
  }
  const float Csq = csprod * csprod;
  __syncthreads();

  // vector read-back (broadcast reads, conflict-free)
  float t1[NQ], t2[NQ], t3[NQ], c0[NQ], s0[NQ];
  {
    const float4* P4 = (const float4*)P;
#define LD4(arr, base, idx) { float4 v = P4[idx]; arr[base]=v.x; arr[base+1]=v.y; arr[base+2]=v.z; arr[base+3]=v.w; }
    LD4(t1, 0, 0) LD4(t1, 4, 1) LD4(t1, 8, 2)
    LD4(t2, 0, 3) LD4(t2, 4, 4) LD4(t2, 8, 5)
    LD4(t3, 0, 6) LD4(t3, 4, 7) LD4(t3, 8, 8)
    LD4(c0, 0, 9) LD4(c0, 4, 10) LD4(c0, 8, 11)
    LD4(s0, 0, 12) LD4(s0, 4, 13) LD4(s0, 8, 14)
#undef LD4
  }

  // ---- layer 0 on |0..0>: per-element product state (rounds 9-11 verified) ----
  float flane = 1.0f;
  #pragma unroll
  for (int k = 0; k < 5; ++k) {
    flane *= ((l5 >> k) & 1) ? s0[4 - k] : c0[4 - k];
  }
  f32x2 s2[64];
  { f32x2 h0; h0.x = c0[11] * flane; h0.y = s0[11] * flane; s2[0] = h0; }
  #pragma unroll
  for (int k = 0; k < 6; ++k) {
    const int W = 1 << k;
    #pragma unroll
    for (int j = 0; j < 64; ++j) {
      if (j >= W) continue;
      s2[j + W] = s2[j] * s0[10 - k];
      s2[j]     = s2[j] * c0[10 - k];
    }
  }

  // ---- layers 1-3 (tan form) ----
  round_rec<1, 0>(s2, t1, lane);
  round_rec<2, 0>(s2, t2, lane);
  round_rec<3, 0>(s2, t3, lane);

  // probabilities (unscaled, packed)
  #pragma unroll
  for (int r = 0; r < 64; ++r) s2[r] = s2[r] * s2[r];

  // Walsh-Hadamard over the 7 register-dim bits
  #pragma unroll
  for (int r = 0; r < 64; ++r) {
    const float u = s2[r].x, v = s2[r].y;
    s2[r].x = u + v;
    s2[r].y = u - v;
  }
  #pragma unroll
  for (int b = 0; b < 6; ++b) {
    const int W = 1 << b;
    #pragma unroll
    for (int r0 = 0; r0 < 64; ++r0) {
      if (r0 & W) continue;
      const int r1 = r0 | W;
      const f32x2 u = s2[r0], v = s2[r1];
      s2[r0] = u + v;
      s2[r1] = u - v;
    }
  }

  // ---- epilogue: 12 signed reductions over lane bits 0-4 (per element) ----
  sfor<0, NQ>([&](auto QC) {
    constexpr int q   = decltype(QC)::v;
    constexpr int RM  = MT.rout[q];
    constexpr int RMH = (RM >> 7) & 31;
    constexpr int RMO = RM & 127;
    float v = (RMO & 1) ? s2[RMO >> 1].y : s2[RMO >> 1].x;
    if constexpr (RMH != 0) {
      const int sx = (__popc(lane & RMH) & 1) << 31;  // odd lane parity -> minus
      v = __int_as_float(__float_as_int(v) ^ sx);
    }
    v += dppf<0xB1>(v);               // xor1
    v += dppf<0x4E>(v);               // xor2
    v += swzf<(4 << 10) | 0x1F>(v);   // xor4
    v += dppf<0x128>(v);              // xor8
    v += swzf<(16 << 10) | 0x1F>(v);  // xor16 (within 32-lane group)
    if (l5 == 0 && row_store < B) out[row_store * NQ + q] = v * Csq;
  });
}

extern "C" void kernel_launch(void* const* d_in, const int* in_sizes, int n_in,
                              void* d_out, int out_size, void* d_ws, size_t ws_size,
                              hipStream_t stream) {
  const float* ang    = (const float*)d_in[0];
  const float* thetas = (const float*)d_in[1];
  float* out          = (float*)d_out;
  const int B = in_sizes[0] / NQ;
  const int waves = (B + 1) / 2;       // 2 elements per wave
  const int threads = 256;
  const int blocks = (waves * 64 + threads - 1) / threads;
  hipLaunchKernelGGL(vqc_kernel, dim3(blocks), dim3(threads), 0, stream,
                     ang, thetas, out, B);
}

// Round 17
// 48.127 us; speedup vs baseline: 1.4303x; 1.2422x over previous
//
#include <hip/hip_runtime.h>

#define NQ 12
#define NL 4

typedef float f32x2 __attribute__((ext_vector_type(2)));

// ---------------------------------------------------------------------------
// Compile-time CNOT tracking as a GF(2) linear map (rounds 1-16, verified).
// RY(l,q) in tan form: mine'[i] = mine[i] + T(i)*mine[i^mk],
//   T(i) = +t iff parity(rm & i) odd else -t; cos factors -> Ctot^2 at end.
// LAYOUT (r9-r11, verified): TWO batch elements per wave.
//   physical lane = (elem << 5) | l5;  global index i = (l5 << 7) | (r<<1) | h
// ROUND 17: r11 source verbatim, ONE change — dppf uses
// __builtin_amdgcn_mov_dpp (single v_mov_b32_dpp) instead of
// update_dpp(0,...) which forces a v_mov 0-init per fetch (2 ops) and
// blocks DPPCombine's mov_dpp+fmac -> v_fmac_f32_dpp fusion.
// ---------------------------------------------------------------------------
struct MaskTab { int mk[NL][NQ]; int rm[NL][NQ]; int rout[NQ]; };

static constexpr MaskTab build_masks() {
  MaskTab T{};
  unsigned col[NQ] = {};
  unsigned inv[NQ] = {};
  for (int k = 0; k < NQ; ++k) { col[k] = 1u << k; inv[k] = 1u << k; }
  for (int l = 0; l < NL; ++l) {
    for (int q = 0; q < NQ; ++q) {
      const int p = NQ - 1 - q;
      T.mk[l][q] = (int)inv[p];
      int rm = 0;
      for (int k = 0; k < NQ; ++k) rm |= (int)(((col[k] >> p) & 1u) << k);
      T.rm[l][q] = rm;
    }
    for (int q = 0; q < NQ - 1; ++q) {
      const int pc = NQ - 1 - q, pt = NQ - 2 - q;
      for (int k = 0; k < NQ; ++k) col[k] ^= ((col[k] >> pc) & 1u) << pt;
      inv[pc] ^= inv[pt];
    }
  }
  for (int q = 0; q < NQ; ++q) {
    const int p = NQ - 1 - q;
    int rm = 0;
    for (int k = 0; k < NQ; ++k) rm |= (int)(((col[k] >> p) & 1u) << k);
    T.rout[q] = rm;
  }
  return T;
}
static constexpr MaskTab MT = build_masks();

// ---------------- compile-time utils ----------------
constexpr int cpar(int j, int m) { return __builtin_popcount((unsigned)(j & m)) & 1; }
constexpr int chb(int m) { return m ? (1 << (31 - __builtin_clz((unsigned)m))) : 0; }
constexpr bool dpp_ok(int d) { return d==1||d==2||d==3||d==7||d==8||d==15; }
constexpr int dpp_ctrl_for(int d) {
  return d==1?0xB1 : d==2?0x4E : d==3?0x1B : d==7?0x141 : d==8?0x128 : 0x140;
}
// 2-DPP compositions kept on VALU: 6=7^1, 12=15^3 (5,10 stay on DS, as r11)
constexpr bool synth2_ok(int d) { return d==6||d==12; }
constexpr int synth_a(int d) { return d==6?0x141 : 0x140; }
constexpr int synth_b(int d) { return d==6?0xB1  : 0x1B; }

template <int V> struct ic_ { static constexpr int v = V; };
template <int I, int N, typename F>
__device__ __forceinline__ void sfor(F&& f) {
  if constexpr (I < N) { f(ic_<I>{}); sfor<I + 1, N>(f); }
}

// ---------------- cross-lane primitives ----------------
// ROUND 17: single-instruction DPP mov (all source lanes active for xor
// patterns -> identical semantics to the update_dpp form used in r4-r16).
template <int CTRL>
__device__ __forceinline__ float dppf(float x) {
  return __int_as_float(__builtin_amdgcn_mov_dpp(__float_as_int(x), CTRL, 0xF, 0xF, false));
}
template <int PAT>
__device__ __forceinline__ float swzf(float x) {
  return __int_as_float(__builtin_amdgcn_ds_swizzle(__float_as_int(x), PAT));
}

__device__ __forceinline__ f32x2 pfma(f32x2 t, f32x2 p, f32x2 s) {
  return __builtin_elementwise_fma(t, p, s);
}

// lane-parity base sign: odd parity -> +t, even -> -t (rounds 2-16 verified).
template <int MASK>
__device__ __forceinline__ float lane_sign(float t, int lane) {
  if constexpr (MASK == 0) return -t;
  else return (__popc(lane & MASK) & 1) ? t : -t;
}

// ---------------- one RY gate (tan form), 2-elem layout ----------------
template <int L, int Q>
__device__ __forceinline__ void gate(f32x2 (&s2)[64], float t, int lane) {
  constexpr int MK  = MT.mk[L][Q];
  constexpr int RM  = MT.rm[L][Q];
  constexpr int MKL = (MK >> 7) & 31;   // lane-xor (physical lane bits 0-4)
  constexpr int MKO = MK & 127;         // register+half xor (index bits 0-6)
  constexpr int RMH = (RM >> 7) & 31;
  constexpr int RMO = RM & 127;
  const float tl  = lane_sign<RMH>(t, lane);
  const float tln = -tl;
  constexpr int M2 = MKO >> 1;   // f32x2-register xor
  constexpr int HS = MKO & 1;    // half swap (index bit 0)

  if constexpr (MKL == 0 && HS == 0) {
    // ---- packed register butterfly; RMO even -> per-register uniform sign ----
    f32x2 tp; tp.x = tl;  tp.y = tl;
    f32x2 tn; tn.x = tln; tn.y = tln;
    constexpr int HB = chb(M2);
    sfor<0, 64>([&](auto RC) {
      constexpr int r0 = decltype(RC)::v;
      if constexpr ((r0 & HB) == 0) {
        constexpr int r1 = r0 ^ M2;
        const f32x2 A = s2[r0], B = s2[r1];
        s2[r0] = pfma(cpar(2*r0, RMO) ? tn : tp, B, A);
        s2[r1] = pfma(cpar(2*r1, RMO) ? tn : tp, A, B);
      }
    });
  } else if constexpr (MKL == 0) {
    // ---- half-swap register gates: scalar FMAs ----
    if constexpr (M2 == 0) {
      sfor<0, 64>([&](auto RC) {
        constexpr int r = decltype(RC)::v;
        const float ax = s2[r].x, ay = s2[r].y;
        s2[r].x = fmaf(cpar(2*r,   RMO) ? tln : tl, ay, ax);
        s2[r].y = fmaf(cpar(2*r+1, RMO) ? tln : tl, ax, ay);
      });
    } else {
      constexpr int HB = chb(M2);
      sfor<0, 64>([&](auto RC) {
        constexpr int r0 = decltype(RC)::v;
        if constexpr ((r0 & HB) == 0) {
          constexpr int r1 = r0 ^ M2;
          const float ax = s2[r0].x, ay = s2[r0].y;
          const float bx = s2[r1].x, by = s2[r1].y;
          s2[r0].x = fmaf(cpar(2*r0,   RMO) ? tln : tl, by, ax);
          s2[r0].y = fmaf(cpar(2*r0+1, RMO) ? tln : tl, bx, ay);
          s2[r1].x = fmaf(cpar(2*r1,   RMO) ? tln : tl, ay, bx);
          s2[r1].y = fmaf(cpar(2*r1+1, RMO) ? tln : tl, ax, by);
        }
      });
    }
  } else if constexpr (dpp_ok(MKL) || synth2_ok(MKL)) {
    // ---- DPP-path cross gates: scalar tied-dst form (DPPCombine target) ----
    auto D = [&](float x) -> float {
      if constexpr (dpp_ok(MKL)) return dppf<dpp_ctrl_for(MKL)>(x);
      else return dppf<synth_b(MKL)>(dppf<synth_a(MKL)>(x));
    };
    if constexpr (M2 == 0) {
      sfor<0, 64>([&](auto RC) {
        constexpr int r = decltype(RC)::v;
        const float sr = cpar(2*r, RMO) ? tln : tl;
        s2[r].x = fmaf(D(s2[r].x), sr, s2[r].x);
        s2[r].y = fmaf(D(s2[r].y), sr, s2[r].y);
      });
    } else {
      constexpr int HB = chb(M2);
      sfor<0, 64>([&](auto RC) {
        constexpr int r0 = decltype(RC)::v;
        if constexpr ((r0 & HB) == 0) {
          constexpr int r1 = r0 ^ M2;
          const float s0v = cpar(2*r0, RMO) ? tln : tl;
          const float s1v = cpar(2*r1, RMO) ? tln : tl;
          const float ax = s2[r0].x, ay = s2[r0].y;
          const float bx = s2[r1].x, by = s2[r1].y;
          s2[r0].x = fmaf(D(bx), s0v, ax);
          s2[r0].y = fmaf(D(by), s0v, ay);
          s2[r1].x = fmaf(D(ax), s1v, bx);
          s2[r1].y = fmaf(D(ay), s1v, by);
        }
      });
    }
  } else {
    // ---- DS swizzle cross gates (masks 5,10,20,24,30; MKO even) ----
    constexpr int PAT = (MKL << 10) | 0x1F;
    f32x2 tp; tp.x = tl;  tp.y = tl;
    f32x2 tn; tn.x = tln; tn.y = tln;
    if constexpr (M2 == 0) {
      sfor<0, 64>([&](auto RC) {
        constexpr int r = decltype(RC)::v;
        f32x2 p; p.x = swzf<PAT>(s2[r].x); p.y = swzf<PAT>(s2[r].y);
        s2[r] = pfma(cpar(2*r, RMO) ? tn : tp, p, s2[r]);
      });
    } else {
      constexpr int HB = chb(M2);
      sfor<0, 64>([&](auto RC) {
        constexpr int r0 = decltype(RC)::v;
        if constexpr ((r0 & HB) == 0) {
          constexpr int r1 = r0 ^ M2;
          f32x2 pa; pa.x = swzf<PAT>(s2[r1].x); pa.y = swzf<PAT>(s2[r1].y);
          f32x2 pb; pb.x = swzf<PAT>(s2[r0].x); pb.y = swzf<PAT>(s2[r0].y);
          s2[r0] = pfma(cpar(2*r0, RMO) ? tn : tp, pa, s2[r0]);
          s2[r1] = pfma(cpar(2*r1, RMO) ? tn : tp, pb, s2[r1]);
        }
      });
    }
  }
}

template <int L, int Q>
__device__ __forceinline__ void round_rec(f32x2 (&s2)[64], const float (&t)[NQ], int lane) {
  if constexpr (Q < NQ) {
    gate<L, Q>(s2, t[Q], lane);
    round_rec<L, Q + 1>(s2, t, lane);
  }
}

__global__ __launch_bounds__(256, 2) void vqc_kernel(const float* __restrict__ ang,
                                                     const float* __restrict__ thetas,
                                                     float* __restrict__ out, int B) {
  const int tid  = blockIdx.x * blockDim.x + threadIdx.x;
  const int gw   = tid >> 6;          // wave index: elements 2gw, 2gw+1
  const int lane = tid & 63;
  const int l5   = lane & 31;
  const int elem = lane >> 5;
  const int row_store = 2 * gw + elem;
  const int row = (row_store < B) ? row_store : (B - 1);   // clamp, no early exit

  // ---- distributed angle prep -> per-wave LDS slab (r10/r11 verified) ----
  // slab per element (64 floats): [0..35] tan(l=1..3,q), [36..47] c0, [48..59] s0
  __shared__ float prep[4][2][64];
  const int wib = threadIdx.x >> 6;
  float* P = &prep[wib][elem][0];

  float csprod;
  {
    const int tau1 = l5;
    const int lq1 = (1 + tau1 / 12) * NQ + (tau1 % 12);
    float sn, cs;
    __sincosf(0.5f * (ang[row * NQ + (tau1 % 12)] + thetas[lq1]), &sn, &cs);
    P[tau1] = __fdividef(sn, cs);
    csprod = cs;
    if (l5 < 16) {
      const int tau2 = l5 + 32;
      if (tau2 < 36) {
        const int q2 = tau2 % 12;
        float sn2, cs2;
        __sincosf(0.5f * (ang[row * NQ + q2] + thetas[3 * NQ + q2]), &sn2, &cs2);
        P[tau2] = __fdividef(sn2, cs2);
        csprod *= cs2;
      } else {
        const int q2 = tau2 - 36;
        float sn2, cs2;
        __sincosf(0.5f * (ang[row * NQ + q2] + thetas[q2]), &sn2, &cs2);
        P[36 + q2] = cs2;
        P[48 + q2] = sn2;
      }
    }
    csprod *= dppf<0xB1>(csprod);
    csprod *= dppf<0x4E>(csprod);
    csprod *= swzf<(4 << 10) | 0x1F>(csprod);
    csprod *= dppf<0x128>(csprod);
    csprod *= swzf<(16 << 10) | 0x1F>(csprod);
  }
  const float Csq = csprod * csprod;
  __syncthreads();

  // vector read-back (broadcast reads, conflict-free)
  float t1[NQ], t2[NQ], t3[NQ], c0[NQ], s0[NQ];
  {
    const float4* P4 = (const float4*)P;
#define LD4(arr, base, idx) { float4 v = P4[idx]; arr[base]=v.x; arr[base+1]=v.y; arr[base+2]=v.z; arr[base+3]=v.w; }
    LD4(t1, 0, 0) LD4(t1, 4, 1) LD4(t1, 8, 2)
    LD4(t2, 0, 3) LD4(t2, 4, 4) LD4(t2, 8, 5)
    LD4(t3, 0, 6) LD4(t3, 4, 7) LD4(t3, 8, 8)
    LD4(c0, 0, 9) LD4(c0, 4, 10) LD4(c0, 8, 11)
    LD4(s0, 0, 12) LD4(s0, 4, 13) LD4(s0, 8, 14)
#undef LD4
  }

  // ---- layer 0 on |0..0>: per-element product state (rounds 9-11 verified) ----
  float flane = 1.0f;
  #pragma unroll
  for (int k = 0; k < 5; ++k) {
    flane *= ((l5 >> k) & 1) ? s0[4 - k] : c0[4 - k];
  }
  f32x2 s2[64];
  { f32x2 h0; h0.x = c0[11] * flane; h0.y = s0[11] * flane; s2[0] = h0; }
  #pragma unroll
  for (int k = 0; k < 6; ++k) {
    const int W = 1 << k;
    #pragma unroll
    for (int j = 0; j < 64; ++j) {
      if (j >= W) continue;
      s2[j + W] = s2[j] * s0[10 - k];
      s2[j]     = s2[j] * c0[10 - k];
    }
  }

  // ---- layers 1-3 (tan form) ----
  round_rec<1, 0>(s2, t1, lane);
  round_rec<2, 0>(s2, t2, lane);
  round_rec<3, 0>(s2, t3, lane);

  // probabilities (unscaled, packed)
  #pragma unroll
  for (int r = 0; r < 64; ++r) s2[r] = s2[r] * s2[r];

  // Walsh-Hadamard over the 7 register-dim bits
  #pragma unroll
  for (int r = 0; r < 64; ++r) {
    const float u = s2[r].x, v = s2[r].y;
    s2[r].x = u + v;
    s2[r].y = u - v;
  }
  #pragma unroll
  for (int b = 0; b < 6; ++b) {
    const int W = 1 << b;
    #pragma unroll
    for (int r0 = 0; r0 < 64; ++r0) {
      if (r0 & W) continue;
      const int r1 = r0 | W;
      const f32x2 u = s2[r0], v = s2[r1];
      s2[r0] = u + v;
      s2[r1] = u - v;
    }
  }

  // ---- epilogue: 12 signed reductions over lane bits 0-4 (per element) ----
  sfor<0, NQ>([&](auto QC) {
    constexpr int q   = decltype(QC)::v;
    constexpr int RM  = MT.rout[q];
    constexpr int RMH = (RM >> 7) & 31;
    constexpr int RMO = RM & 127;
    float v = (RMO & 1) ? s2[RMO >> 1].y : s2[RMO >> 1].x;
    if constexpr (RMH != 0) {
      const int sx = (__popc(lane & RMH) & 1) << 31;  // odd lane parity -> minus
      v = __int_as_float(__float_as_int(v) ^ sx);
    }
    v += dppf<0xB1>(v);               // xor1
    v += dppf<0x4E>(v);               // xor2
    v += swzf<(4 << 10) | 0x1F>(v);   // xor4
    v += dppf<0x128>(v);              // xor8
    v += swzf<(16 << 10) | 0x1F>(v);  // xor16 (within 32-lane group)
    if (l5 == 0 && row_store < B) out[row_store * NQ + q] = v * Csq;
  });
}

extern "C" void kernel_launch(void* const* d_in, const int* in_sizes, int n_in,
                              void* d_out, int out_size, void* d_ws, size_t ws_size,
                              hipStream_t stream) {
  const float* ang    = (const float*)d_in[0];
  const float* thetas = (const float*)d_in[1];
  float* out          = (float*)d_out;
  const int B = in_sizes[0] / NQ;
  const int waves = (B + 1) / 2;       // 2 elements per wave
  const int threads = 256;
  const int blocks = (waves * 64 + threads - 1) / threads;
  hipLaunchKernelGGL(vqc_kernel, dim3(blocks), dim3(threads), 0, stream,
                     ang, thetas, out, B);
}